// Round 5
// baseline (55.914 us; speedup 1.0000x reference)
//
#include <hip/hip_runtime.h>
#include <cmath>

#define EPSN 1e-12f

typedef _Float16 half8 __attribute__((ext_vector_type(8)));
typedef _Float16 half4 __attribute__((ext_vector_type(4)));
typedef float f32x4 __attribute__((ext_vector_type(4)));

// ---------------------------------------------------------------------------
// scores_kernel: one block per (b, n, half). 256 threads = 4 waves.
// Thread t owns 16B piece (t&7) of tokens (t>>3)+{0,32,64,96} -> each wave's
// global load covers 8 contiguous 128B segments (coalesced). Per-token ss
// reduced over 8 same-wave lanes. f16 hi/lo 3-term MFMA (validated r2-r4),
// inv-norm in epilogue. Register ping-pong prefetch + lgkmcnt-only barriers
// keep next chunk's loads in flight across barriers.
// ---------------------------------------------------------------------------
__global__ __launch_bounds__(256, 4) void scores_kernel(
    const float* __restrict__ qr, const float* __restrict__ doc,
    const int* __restrict__ mask, float* __restrict__ pmax) {
    __shared__ __align__(16) char Aimg[16384];   // [qt2][kstep4][hl2][1024B]
    __shared__ __align__(16) char Bimg[16384];   // [tile8][hl2][kg4*16+col][16B]
    __shared__ float invS[128];
    __shared__ int   maskS[128];
    __shared__ float wq[4][32];

    int t = threadIdx.x, g = blockIdx.x;
    int bn = g >> 1, h = g & 1, b = g >> 5;
    int w = t >> 6, lane = t & 63, col = lane & 15;

    int u  = t >> 3;                  // token base: tokens u+32j
    int kq = t & 7;                   // 16B piece within the 128B chunk slice

    const float4* dbase = (const float4*)(doc + ((size_t)bn * 256 + h * 128) * 128);
    int fi0 = u * 32 + kq;            // + 1024*j + 8*c

    // ---- chunk-0 prefetch (coalesced 128B segments) ----
    float4 rA0 = dbase[fi0 + 0], rA1 = dbase[fi0 + 1024];
    float4 rA2 = dbase[fi0 + 2048], rA3 = dbase[fi0 + 3072];
    float4 rB0, rB1, rB2, rB3;

    if (t < 128) maskS[t] = mask[bn * 256 + h * 128 + t];

    // ---- q prologue: normalize + f16 hi/lo split + A-image (validated) ----
    {
        int row = t >> 3, jb = t & 7;
        const float4* qsrc = (const float4*)(qr + ((size_t)b * 32 + row) * 128 + jb * 16);
        float4 v[4];
#pragma unroll
        for (int i = 0; i < 4; ++i) v[i] = qsrc[i];
        float ss = 0.f;
#pragma unroll
        for (int i = 0; i < 4; ++i)
            ss += v[i].x*v[i].x + v[i].y*v[i].y + v[i].z*v[i].z + v[i].w*v[i].w;
        ss += __shfl_xor(ss, 1); ss += __shfl_xor(ss, 2); ss += __shfl_xor(ss, 4);
        float inv = 1.0f / fmaxf(sqrtf(ss), EPSN);
        int qt = row >> 4, kstep = jb >> 1;
#pragma unroll
        for (int khh = 0; khh < 2; ++khh) {
            float xs[8] = { v[2*khh].x,   v[2*khh].y,   v[2*khh].z,   v[2*khh].w,
                            v[2*khh+1].x, v[2*khh+1].y, v[2*khh+1].z, v[2*khh+1].w };
            half8 hh, hl;
#pragma unroll
            for (int e = 0; e < 8; ++e) {
                float x = xs[e] * inv;
                _Float16 hv = (_Float16)x;
                hh[e] = hv;
                hl[e] = (_Float16)(x - (float)hv);
            }
            int quad = (jb & 1) * 2 + khh;
            int base = ((qt * 4 + kstep) * 2) * 1024 + ((row & 15) + quad * 16) * 16;
            *(half8*)(Aimg + base)        = hh;
            *(half8*)(Aimg + base + 1024) = hl;
        }
    }
    asm volatile("s_waitcnt lgkmcnt(0)" ::: "memory");
    __builtin_amdgcn_s_barrier();

    f32x4 acc[2][2];
    f32x4 zero = {0.f, 0.f, 0.f, 0.f};
    acc[0][0] = zero; acc[0][1] = zero; acc[1][0] = zero; acc[1][1] = zero;
    float ss0 = 0.f, ss1 = 0.f, ss2 = 0.f, ss3 = 0.f;

    // B write base: tile=(u>>4)+2j, colb=u&15, kg=kq>>1, parity=kq&1; j adds 4096B
    int bwbase = (u >> 4) * 2048 + (((kq >> 1) * 16 + (u & 15)) << 4) + (kq & 1) * 8;

#define CVT4(P, HH, HL) do {                                                  \
    float xs_[4] = { P.x, P.y, P.z, P.w };                                    \
    _Pragma("unroll")                                                         \
    for (int e_ = 0; e_ < 4; ++e_) {                                          \
        float x_ = xs_[e_]; _Float16 hv_ = (_Float16)x_;                      \
        HH[e_] = hv_; HL[e_] = (_Float16)(x_ - (float)hv_);                   \
    }                                                                         \
} while (0)

#define CHUNK(C, P0, P1, P2, P3, N0, N1, N2, N3, ISLAST) do {                 \
    if (!(ISLAST)) {                                                          \
        N0 = dbase[fi0 + (C + 1) * 8];        N1 = dbase[fi0 + 1024 + (C + 1) * 8]; \
        N2 = dbase[fi0 + 2048 + (C + 1) * 8]; N3 = dbase[fi0 + 3072 + (C + 1) * 8]; \
    }                                                                         \
    ss0 += P0.x*P0.x + P0.y*P0.y + P0.z*P0.z + P0.w*P0.w;                     \
    ss1 += P1.x*P1.x + P1.y*P1.y + P1.z*P1.z + P1.w*P1.w;                     \
    ss2 += P2.x*P2.x + P2.y*P2.y + P2.z*P2.z + P2.w*P2.w;                     \
    ss3 += P3.x*P3.x + P3.y*P3.y + P3.z*P3.z + P3.w*P3.w;                     \
    {                                                                         \
        half4 h0, l0, h1, l1, h2, l2, h3, l3;                                 \
        CVT4(P0, h0, l0); CVT4(P1, h1, l1); CVT4(P2, h2, l2); CVT4(P3, h3, l3); \
        *(half4*)(Bimg + bwbase + 0)            = h0;                         \
        *(half4*)(Bimg + bwbase + 1024)         = l0;                         \
        *(half4*)(Bimg + bwbase + 4096)         = h1;                         \
        *(half4*)(Bimg + bwbase + 4096 + 1024)  = l1;                         \
        *(half4*)(Bimg + bwbase + 8192)         = h2;                         \
        *(half4*)(Bimg + bwbase + 8192 + 1024)  = l2;                         \
        *(half4*)(Bimg + bwbase + 12288)        = h3;                         \
        *(half4*)(Bimg + bwbase + 12288 + 1024) = l3;                         \
    }                                                                         \
    asm volatile("s_waitcnt lgkmcnt(0)" ::: "memory");                        \
    __builtin_amdgcn_s_barrier();                                             \
    if (ISLAST) {                                                             \
        ss0 += __shfl_xor(ss0, 1); ss0 += __shfl_xor(ss0, 2); ss0 += __shfl_xor(ss0, 4); \
        ss1 += __shfl_xor(ss1, 1); ss1 += __shfl_xor(ss1, 2); ss1 += __shfl_xor(ss1, 4); \
        ss2 += __shfl_xor(ss2, 1); ss2 += __shfl_xor(ss2, 2); ss2 += __shfl_xor(ss2, 4); \
        ss3 += __shfl_xor(ss3, 1); ss3 += __shfl_xor(ss3, 2); ss3 += __shfl_xor(ss3, 4); \
        if (kq == 0) {                                                        \
            invS[u]      = maskS[u]      ? (1.0f / fmaxf(sqrtf(ss0), EPSN)) : 0.0f; \
            invS[u + 32] = maskS[u + 32] ? (1.0f / fmaxf(sqrtf(ss1), EPSN)) : 0.0f; \
            invS[u + 64] = maskS[u + 64] ? (1.0f / fmaxf(sqrtf(ss2), EPSN)) : 0.0f; \
            invS[u + 96] = maskS[u + 96] ? (1.0f / fmaxf(sqrtf(ss3), EPSN)) : 0.0f; \
        }                                                                     \
    }                                                                         \
    {                                                                         \
        int lo = lane << 4;                                                   \
        half8 a0h = *(const half8*)(Aimg + (((C) * 2 + 0) << 10) + lo);       \
        half8 a0l = *(const half8*)(Aimg + (((C) * 2 + 1) << 10) + lo);       \
        half8 a1h = *(const half8*)(Aimg + (((4 + (C)) * 2 + 0) << 10) + lo); \
        half8 a1l = *(const half8*)(Aimg + (((4 + (C)) * 2 + 1) << 10) + lo); \
        _Pragma("unroll")                                                     \
        for (int nt = 0; nt < 2; ++nt) {                                      \
            int tile = w * 2 + nt;                                            \
            half8 bh = *(const half8*)(Bimg + tile * 2048 + lo);              \
            half8 bl = *(const half8*)(Bimg + tile * 2048 + 1024 + lo);       \
            acc[0][nt] = __builtin_amdgcn_mfma_f32_16x16x32_f16(a0l, bh, acc[0][nt], 0, 0, 0); \
            acc[0][nt] = __builtin_amdgcn_mfma_f32_16x16x32_f16(a0h, bl, acc[0][nt], 0, 0, 0); \
            acc[0][nt] = __builtin_amdgcn_mfma_f32_16x16x32_f16(a0h, bh, acc[0][nt], 0, 0, 0); \
            acc[1][nt] = __builtin_amdgcn_mfma_f32_16x16x32_f16(a1l, bh, acc[1][nt], 0, 0, 0); \
            acc[1][nt] = __builtin_amdgcn_mfma_f32_16x16x32_f16(a1h, bl, acc[1][nt], 0, 0, 0); \
            acc[1][nt] = __builtin_amdgcn_mfma_f32_16x16x32_f16(a1h, bh, acc[1][nt], 0, 0, 0); \
        }                                                                     \
    }                                                                         \
    asm volatile("s_waitcnt lgkmcnt(0)" ::: "memory");                        \
    __builtin_amdgcn_s_barrier();                                             \
} while (0)

    CHUNK(0, rA0, rA1, rA2, rA3, rB0, rB1, rB2, rB3, false);
    CHUNK(1, rB0, rB1, rB2, rB3, rA0, rA1, rA2, rA3, false);
    CHUNK(2, rA0, rA1, rA2, rA3, rB0, rB1, rB2, rB3, false);
    CHUNK(3, rB0, rB1, rB2, rB3, rA0, rA1, rA2, rA3, true);
#undef CHUNK
#undef CVT4

    // ---- epilogue: inv-norm, max over this block's 128 tokens (validated) ----
    float inv0 = invS[w * 32 + col];
    float inv1 = invS[w * 32 + 16 + col];
    float m8[8];
#pragma unroll
    for (int qt = 0; qt < 2; ++qt)
#pragma unroll
        for (int rr = 0; rr < 4; ++rr)
            m8[qt * 4 + rr] = fmaxf(acc[qt][0][rr] * inv0, acc[qt][1][rr] * inv1);
#pragma unroll
    for (int off = 1; off < 16; off <<= 1)
#pragma unroll
        for (int i = 0; i < 8; ++i) m8[i] = fmaxf(m8[i], __shfl_xor(m8[i], off));
    if (col == 0) {
        int rg = lane >> 4;   // C/D: row = (lane>>4)*4 + reg (m89-verified)
#pragma unroll
        for (int qt = 0; qt < 2; ++qt)
#pragma unroll
            for (int rr = 0; rr < 4; ++rr) wq[w][qt * 16 + rg * 4 + rr] = m8[qt * 4 + rr];
    }
    __syncthreads();
    if (w == 0 && lane < 32) {
        float v = fmaxf(fmaxf(wq[0][lane], wq[1][lane]), fmaxf(wq[2][lane], wq[3][lane]));
        pmax[(size_t)g * 32 + lane] = v;
    }
}

// ---------------------------------------------------------------------------
// loss_kernel: single block, 1024 threads. Thread t combines bn=t's two
// half-block maxes into scores, then all 16384 pair losses + reduce.
// ---------------------------------------------------------------------------
__global__ __launch_bounds__(1024) void loss_kernel(const float* __restrict__ pmax,
                                                    const float* __restrict__ labels,
                                                    float* __restrict__ out) {
    __shared__ float scL[1024];
    __shared__ float labL[2048];
    __shared__ float wsum[16];
    int t = threadIdx.x;
    labL[t] = labels[t];
    labL[t + 1024] = labels[t + 1024];
    {
        const float4* p0 = (const float4*)(pmax + (size_t)t * 64);
        float s = 0.f;
#pragma unroll
        for (int i = 0; i < 8; ++i) {
            float4 a = p0[i];        // half 0, q = 4i..4i+3
            float4 bq = p0[i + 8];   // half 1
            s += fmaxf(a.x, bq.x) + fmaxf(a.y, bq.y) + fmaxf(a.z, bq.z) + fmaxf(a.w, bq.w);
        }
        scL[t] = s;
    }
    __syncthreads();
    float total = 0.f;
#pragma unroll
    for (int it = 0; it < 16; ++it) {
        int p = t + it * 1024;
        int b = p >> 8, ij = p & 255, i = ij >> 4, j = ij & 15;
        float ysi = labL[b * 32 + i], ysj = labL[b * 32 + j];
        if (ysi - ysj > 0.f) {
            float wgt = fabsf(labL[b * 32 + 16 + i] - labL[b * 32 + 16 + j]);
            float d = (i <= j) ? (scL[b * 16 + i] - scL[b * 16 + j]) : 0.f;
            total += log1pf(expf(-d)) * wgt;
        }
    }
#pragma unroll
    for (int off = 1; off < 64; off <<= 1) total += __shfl_xor(total, off);
    int lane = t & 63;
    if (lane == 0) wsum[t >> 6] = total;
    __syncthreads();
    if (t < 64) {
        float v = (t < 16) ? wsum[t] : 0.f;
#pragma unroll
        for (int off = 1; off < 64; off <<= 1) v += __shfl_xor(v, off);
        if (t == 0) out[0] = v;
    }
}

// ---------------------------------------------------------------------------
extern "C" void kernel_launch(void* const* d_in, const int* in_sizes, int n_in,
                              void* d_out, int out_size, void* d_ws, size_t ws_size,
                              hipStream_t stream) {
    const float* qr     = (const float*)d_in[0];   // (64,32,128) f32
    const float* doc    = (const float*)d_in[1];   // (64,16,256,128) f32
    const int*   dmask  = (const int*)d_in[2];     // (64,16,256) i32
    const float* labels = (const float*)d_in[3];   // (64,32) f32
    float* out = (float*)d_out;

    float* pmax = (float*)d_ws;                    // 2048*32 f32 = 256 KB

    scores_kernel<<<2048, 256, 0, stream>>>(qr, doc, dmask, pmax);
    loss_kernel<<<1, 1024, 0, stream>>>(pmax, labels, out);
}

// Round 6
// 45.894 us; speedup vs baseline: 1.2183x; 1.2183x over previous
//
#include <hip/hip_runtime.h>
#include <cmath>

#define EPSN 1e-12f

typedef _Float16 half8 __attribute__((ext_vector_type(8)));
typedef float f32x4 __attribute__((ext_vector_type(4)));

// ---------------------------------------------------------------------------
// scores_kernel: one block per bn (grid 1024 = exactly 4 blocks/CU).
// Each block processes BOTH 128-token tiles of its (b,n) with a continuous
// register ping-pong prefetch chain across the tile boundary. Hot paths
// (load mapping tok=t&127/kh=t>>7, f16 hi/lo CVT, B-image layout, 3-term
// MFMA, ssPart/invS) are r4-exact (validated, 34.9 µs total).
// Per-tile epilogue folds maxes into wq (tile 0: write; tile 1: fmax-merge,
// same thread -> no extra barrier); final reduce writes scores[bn] directly.
// ---------------------------------------------------------------------------
__global__ __launch_bounds__(256, 4) void scores_kernel(
    const float* __restrict__ qr, const float* __restrict__ doc,
    const int* __restrict__ mask, float* __restrict__ scores) {
    __shared__ __align__(16) char Aimg[16384];   // [qt2][kstep4][hl2][1024B]
    __shared__ __align__(16) char Bimg[16384];   // [tile8][hl2][kg4*16+col][16B]
    __shared__ float ssPart[256];
    __shared__ float invS[128];
    __shared__ int   maskS[256];
    __shared__ float wq[4][32];

    int t = threadIdx.x, g = blockIdx.x;         // g == bn
    int b = g >> 4;
    int w = t >> 6, lane = t & 63, col = lane & 15;
    int tok = t & 127, kh = t >> 7;

    // ---- chunk (0,0) prefetch immediately; tile h adds 4096 float4s ----
    const float4* dsrc = (const float4*)(doc + ((size_t)g * 256 + tok) * 128) + kh * 4;
    float4 rA0 = dsrc[0], rA1 = dsrc[1], rA2 = dsrc[2], rA3 = dsrc[3];
    float4 rB0, rB1, rB2, rB3;
    maskS[t] = mask[g * 256 + t];                // both tiles' masks

    // ---- q prologue: normalize + f16 hi/lo split + A-image (r4-exact) ----
    {
        int row = t >> 3, jb = t & 7;
        const float4* qsrc = (const float4*)(qr + ((size_t)b * 32 + row) * 128 + jb * 16);
        float4 v[4];
#pragma unroll
        for (int i = 0; i < 4; ++i) v[i] = qsrc[i];
        float ss = 0.f;
#pragma unroll
        for (int i = 0; i < 4; ++i)
            ss += v[i].x*v[i].x + v[i].y*v[i].y + v[i].z*v[i].z + v[i].w*v[i].w;
        ss += __shfl_xor(ss, 1); ss += __shfl_xor(ss, 2); ss += __shfl_xor(ss, 4);
        float inv = 1.0f / fmaxf(sqrtf(ss), EPSN);
        int qt = row >> 4, kstep = jb >> 1;
#pragma unroll
        for (int khh = 0; khh < 2; ++khh) {
            float xs[8] = { v[2*khh].x,   v[2*khh].y,   v[2*khh].z,   v[2*khh].w,
                            v[2*khh+1].x, v[2*khh+1].y, v[2*khh+1].z, v[2*khh+1].w };
            half8 hh, hl;
#pragma unroll
            for (int e = 0; e < 8; ++e) {
                float x = xs[e] * inv;
                _Float16 hv = (_Float16)x;
                hh[e] = hv;
                hl[e] = (_Float16)(x - (float)hv);
            }
            int quad = (jb & 1) * 2 + khh;
            int base = ((qt * 4 + kstep) * 2) * 1024 + ((row & 15) + quad * 16) * 16;
            *(half8*)(Aimg + base)        = hh;
            *(half8*)(Aimg + base + 1024) = hl;
        }
    }
    asm volatile("s_waitcnt lgkmcnt(0)" ::: "memory");
    __builtin_amdgcn_s_barrier();

    f32x4 acc[2][2];
    f32x4 zero = {0.f, 0.f, 0.f, 0.f};
    acc[0][0] = zero; acc[0][1] = zero; acc[1][0] = zero; acc[1][1] = zero;
    float ss_d = 0.f;

    int tile8 = tok >> 4;
    int bo_base = tile8 * 2048 + (2 * kh) * 256 + (tok & 15) * 16;

#define CHUNK(H, C, P0, P1, P2, P3, N0, N1, N2, N3, PREF, NEXTOFF, LASTC) do { \
    if (PREF) {                                                               \
        N0 = dsrc[(NEXTOFF) + 0]; N1 = dsrc[(NEXTOFF) + 1];                   \
        N2 = dsrc[(NEXTOFF) + 2]; N3 = dsrc[(NEXTOFF) + 3];                   \
    }                                                                         \
    ss_d += P0.x*P0.x + P0.y*P0.y + P0.z*P0.z + P0.w*P0.w;                    \
    ss_d += P1.x*P1.x + P1.y*P1.y + P1.z*P1.z + P1.w*P1.w;                    \
    ss_d += P2.x*P2.x + P2.y*P2.y + P2.z*P2.z + P2.w*P2.w;                    \
    ss_d += P3.x*P3.x + P3.y*P3.y + P3.z*P3.z + P3.w*P3.w;                    \
    {                                                                         \
        float xa[8] = { P0.x, P0.y, P0.z, P0.w, P1.x, P1.y, P1.z, P1.w };     \
        float xb[8] = { P2.x, P2.y, P2.z, P2.w, P3.x, P3.y, P3.z, P3.w };     \
        half8 hha, hla, hhb, hlb;                                             \
        _Pragma("unroll")                                                     \
        for (int e = 0; e < 8; ++e) {                                         \
            float x = xa[e]; _Float16 hv = (_Float16)x;                       \
            hha[e] = hv; hla[e] = (_Float16)(x - (float)hv);                  \
            float y = xb[e]; _Float16 hw = (_Float16)y;                       \
            hhb[e] = hw; hlb[e] = (_Float16)(y - (float)hw);                  \
        }                                                                     \
        *(half8*)(Bimg + bo_base)              = hha;                         \
        *(half8*)(Bimg + bo_base + 1024)       = hla;                         \
        *(half8*)(Bimg + bo_base + 256)        = hhb;                         \
        *(half8*)(Bimg + bo_base + 256 + 1024) = hlb;                         \
    }                                                                         \
    if (LASTC) { ssPart[t] = ss_d; ss_d = 0.f; }                              \
    asm volatile("s_waitcnt lgkmcnt(0)" ::: "memory");                        \
    __builtin_amdgcn_s_barrier();                                             \
    if ((LASTC) && t < 128) {                                                 \
        float sst = ssPart[t] + ssPart[t + 128];                              \
        invS[t] = maskS[((H) << 7) | t] ? (1.0f / fmaxf(sqrtf(sst), EPSN)) : 0.0f; \
    }                                                                         \
    {                                                                         \
        int lo = lane << 4;                                                   \
        half8 a0h = *(const half8*)(Aimg + (((C) * 2 + 0) << 10) + lo);       \
        half8 a0l = *(const half8*)(Aimg + (((C) * 2 + 1) << 10) + lo);       \
        half8 a1h = *(const half8*)(Aimg + (((4 + (C)) * 2 + 0) << 10) + lo); \
        half8 a1l = *(const half8*)(Aimg + (((4 + (C)) * 2 + 1) << 10) + lo); \
        _Pragma("unroll")                                                     \
        for (int nt = 0; nt < 2; ++nt) {                                      \
            int tile = w * 2 + nt;                                            \
            half8 bh = *(const half8*)(Bimg + tile * 2048 + lo);              \
            half8 bl = *(const half8*)(Bimg + tile * 2048 + 1024 + lo);       \
            acc[0][nt] = __builtin_amdgcn_mfma_f32_16x16x32_f16(a0l, bh, acc[0][nt], 0, 0, 0); \
            acc[0][nt] = __builtin_amdgcn_mfma_f32_16x16x32_f16(a0h, bl, acc[0][nt], 0, 0, 0); \
            acc[0][nt] = __builtin_amdgcn_mfma_f32_16x16x32_f16(a0h, bh, acc[0][nt], 0, 0, 0); \
            acc[1][nt] = __builtin_amdgcn_mfma_f32_16x16x32_f16(a1l, bh, acc[1][nt], 0, 0, 0); \
            acc[1][nt] = __builtin_amdgcn_mfma_f32_16x16x32_f16(a1h, bl, acc[1][nt], 0, 0, 0); \
            acc[1][nt] = __builtin_amdgcn_mfma_f32_16x16x32_f16(a1h, bh, acc[1][nt], 0, 0, 0); \
        }                                                                     \
    }                                                                         \
    asm volatile("s_waitcnt lgkmcnt(0)" ::: "memory");                        \
    __builtin_amdgcn_s_barrier();                                             \
} while (0)

#define EPI_TILE(FIRST) do {                                                  \
    float inv0 = invS[w * 32 + col];                                          \
    float inv1 = invS[w * 32 + 16 + col];                                     \
    float m8[8];                                                              \
    _Pragma("unroll")                                                         \
    for (int qt = 0; qt < 2; ++qt)                                            \
        _Pragma("unroll")                                                     \
        for (int rr = 0; rr < 4; ++rr)                                        \
            m8[qt * 4 + rr] = fmaxf(acc[qt][0][rr] * inv0, acc[qt][1][rr] * inv1); \
    _Pragma("unroll")                                                         \
    for (int off = 1; off < 16; off <<= 1)                                    \
        _Pragma("unroll")                                                     \
        for (int i = 0; i < 8; ++i) m8[i] = fmaxf(m8[i], __shfl_xor(m8[i], off)); \
    if (col == 0) {                                                           \
        int rg = lane >> 4;   /* C/D: row = (lane>>4)*4 + reg (m89) */        \
        _Pragma("unroll")                                                     \
        for (int qt = 0; qt < 2; ++qt)                                        \
            _Pragma("unroll")                                                 \
            for (int rr = 0; rr < 4; ++rr) {                                  \
                int idx = qt * 16 + rg * 4 + rr;                              \
                wq[w][idx] = (FIRST) ? m8[qt * 4 + rr]                        \
                                     : fmaxf(wq[w][idx], m8[qt * 4 + rr]);    \
            }                                                                 \
    }                                                                         \
} while (0)

    // tile 0 (tokens 0-127): chunks 0..3; chunk 3 prefetches tile 1 chunk 0
    CHUNK(0, 0, rA0, rA1, rA2, rA3, rB0, rB1, rB2, rB3, 1, 8,    0);
    CHUNK(0, 1, rB0, rB1, rB2, rB3, rA0, rA1, rA2, rA3, 1, 16,   0);
    CHUNK(0, 2, rA0, rA1, rA2, rA3, rB0, rB1, rB2, rB3, 1, 24,   0);
    CHUNK(0, 3, rB0, rB1, rB2, rB3, rA0, rA1, rA2, rA3, 1, 4096, 1);
    EPI_TILE(true);
    acc[0][0] = zero; acc[0][1] = zero; acc[1][0] = zero; acc[1][1] = zero;
    // tile 1 (tokens 128-255)
    CHUNK(1, 0, rA0, rA1, rA2, rA3, rB0, rB1, rB2, rB3, 1, 4104, 0);
    CHUNK(1, 1, rB0, rB1, rB2, rB3, rA0, rA1, rA2, rA3, 1, 4112, 0);
    CHUNK(1, 2, rA0, rA1, rA2, rA3, rB0, rB1, rB2, rB3, 1, 4120, 0);
    CHUNK(1, 3, rB0, rB1, rB2, rB3, rA0, rA1, rA2, rA3, 0, 0,    1);
    EPI_TILE(false);
#undef CHUNK
#undef EPI_TILE

    // ---- final: max over 4 waves, sum over 32 q -> scores[bn] ----
    asm volatile("s_waitcnt lgkmcnt(0)" ::: "memory");
    __builtin_amdgcn_s_barrier();
    if (w == 0) {
        float v = 0.f;
        if (lane < 32)
            v = fmaxf(fmaxf(wq[0][lane], wq[1][lane]), fmaxf(wq[2][lane], wq[3][lane]));
#pragma unroll
        for (int off = 1; off < 64; off <<= 1) v += __shfl_xor(v, off);
        if (lane == 0) scores[g] = v;
    }
}

// ---------------------------------------------------------------------------
// loss_kernel: single block, 1024 threads (r5-validated pair logic, direct
// scores input). 16384 pairs -> scalar.
// ---------------------------------------------------------------------------
__global__ __launch_bounds__(1024) void loss_kernel(const float* __restrict__ scores,
                                                    const float* __restrict__ labels,
                                                    float* __restrict__ out) {
    __shared__ float scL[1024];
    __shared__ float labL[2048];
    __shared__ float wsum[16];
    int t = threadIdx.x;
    labL[t] = labels[t];
    labL[t + 1024] = labels[t + 1024];
    scL[t] = scores[t];
    __syncthreads();
    float total = 0.f;
#pragma unroll
    for (int it = 0; it < 16; ++it) {
        int p = t + it * 1024;
        int b = p >> 8, ij = p & 255, i = ij >> 4, j = ij & 15;
        float ysi = labL[b * 32 + i], ysj = labL[b * 32 + j];
        if (ysi - ysj > 0.f) {
            float wgt = fabsf(labL[b * 32 + 16 + i] - labL[b * 32 + 16 + j]);
            float d = (i <= j) ? (scL[b * 16 + i] - scL[b * 16 + j]) : 0.f;
            total += log1pf(expf(-d)) * wgt;
        }
    }
#pragma unroll
    for (int off = 1; off < 64; off <<= 1) total += __shfl_xor(total, off);
    int lane = t & 63;
    if (lane == 0) wsum[t >> 6] = total;
    __syncthreads();
    if (t < 64) {
        float v = (t < 16) ? wsum[t] : 0.f;
#pragma unroll
        for (int off = 1; off < 64; off <<= 1) v += __shfl_xor(v, off);
        if (t == 0) out[0] = v;
    }
}

// ---------------------------------------------------------------------------
extern "C" void kernel_launch(void* const* d_in, const int* in_sizes, int n_in,
                              void* d_out, int out_size, void* d_ws, size_t ws_size,
                              hipStream_t stream) {
    const float* qr     = (const float*)d_in[0];   // (64,32,128) f32
    const float* doc    = (const float*)d_in[1];   // (64,16,256,128) f32
    const int*   dmask  = (const int*)d_in[2];     // (64,16,256) i32
    const float* labels = (const float*)d_in[3];   // (64,32) f32
    float* out = (float*)d_out;

    float* scores = (float*)d_ws;                  // 1024 f32

    scores_kernel<<<1024, 256, 0, stream>>>(qr, doc, dmask, scores);
    loss_kernel<<<1, 1024, 0, stream>>>(scores, labels, out);
}

// Round 8
// 35.092 us; speedup vs baseline: 1.5934x; 1.3078x over previous
//
#include <hip/hip_runtime.h>
#include <cmath>

#define EPSN 1e-12f

typedef _Float16 half8 __attribute__((ext_vector_type(8)));
typedef float f32x4 __attribute__((ext_vector_type(4)));

// ---------------------------------------------------------------------------
// scores_kernel: r4-EXACT (validated 34.9 us total). One block per
// (b, n, half). 256 threads = 4 waves. Thread (tok=t&127, kh=t>>7) owns 64B
// of its token's row per K-chunk. 4 K-chunks of 32; f16 hi/lo 3-term MFMA;
// fp32 sum-of-squares in regs, inv-norm in epilogue. Register ping-pong
// prefetch + lgkmcnt-only barriers keep loads in flight across barriers.
// Output: pmax[g*32 + q] = per-q max over this block's 128 tokens.
// ---------------------------------------------------------------------------
__global__ __launch_bounds__(256, 4) void scores_kernel(
    const float* __restrict__ qr, const float* __restrict__ doc,
    const int* __restrict__ mask, float* __restrict__ pmax) {
    __shared__ __align__(16) char Aimg[16384];   // [qt2][kstep4][hl2][1024B]
    __shared__ __align__(16) char Bimg[16384];   // [tile8][hl2][kg4*16+col][16B]
    __shared__ float ssPart[256];
    __shared__ float invS[128];
    __shared__ float wq[4][32];

    int t = threadIdx.x, g = blockIdx.x;
    int bn = g >> 1, h = g & 1, b = g >> 5;
    int w = t >> 6, lane = t & 63, col = lane & 15;
    int tok = t & 127, kh = t >> 7;

    // ---- issue chunk-0 prefetch immediately ----
    const float4* dsrc = (const float4*)(doc + ((size_t)bn * 256 + h * 128 + tok) * 128) + kh * 4;
    float4 rA0 = dsrc[0], rA1 = dsrc[1], rA2 = dsrc[2], rA3 = dsrc[3];
    float4 rB0, rB1, rB2, rB3;
    int mymask = 0;
    if (t < 128) mymask = mask[bn * 256 + h * 128 + t];

    // ---- q prologue: normalize + f16 hi/lo split + A-image (validated) ----
    {
        int row = t >> 3, jb = t & 7;
        const float4* qsrc = (const float4*)(qr + ((size_t)b * 32 + row) * 128 + jb * 16);
        float4 v[4];
#pragma unroll
        for (int i = 0; i < 4; ++i) v[i] = qsrc[i];
        float ss = 0.f;
#pragma unroll
        for (int i = 0; i < 4; ++i)
            ss += v[i].x*v[i].x + v[i].y*v[i].y + v[i].z*v[i].z + v[i].w*v[i].w;
        ss += __shfl_xor(ss, 1); ss += __shfl_xor(ss, 2); ss += __shfl_xor(ss, 4);
        float inv = 1.0f / fmaxf(sqrtf(ss), EPSN);
        int qt = row >> 4, kstep = jb >> 1;
#pragma unroll
        for (int khh = 0; khh < 2; ++khh) {
            float xs[8] = { v[2*khh].x,   v[2*khh].y,   v[2*khh].z,   v[2*khh].w,
                            v[2*khh+1].x, v[2*khh+1].y, v[2*khh+1].z, v[2*khh+1].w };
            half8 hh, hl;
#pragma unroll
            for (int e = 0; e < 8; ++e) {
                float x = xs[e] * inv;
                _Float16 hv = (_Float16)x;
                hh[e] = hv;
                hl[e] = (_Float16)(x - (float)hv);
            }
            int quad = (jb & 1) * 2 + khh;
            int base = ((qt * 4 + kstep) * 2) * 1024 + ((row & 15) + quad * 16) * 16;
            *(half8*)(Aimg + base)        = hh;
            *(half8*)(Aimg + base + 1024) = hl;
        }
    }
    asm volatile("s_waitcnt lgkmcnt(0)" ::: "memory");
    __builtin_amdgcn_s_barrier();

    f32x4 acc[2][2];
    f32x4 zero = {0.f, 0.f, 0.f, 0.f};
    acc[0][0] = zero; acc[0][1] = zero; acc[1][0] = zero; acc[1][1] = zero;
    float ss_d = 0.f;

    int tile8 = tok >> 4;
    int bo_base = tile8 * 2048 + (2 * kh) * 256 + (tok & 15) * 16;

#define CHUNK(C, P0, P1, P2, P3, N0, N1, N2, N3, ISLAST) do {                 \
    if (!(ISLAST)) {                                                          \
        N0 = dsrc[(C + 1) * 8 + 0]; N1 = dsrc[(C + 1) * 8 + 1];               \
        N2 = dsrc[(C + 1) * 8 + 2]; N3 = dsrc[(C + 1) * 8 + 3];               \
    }                                                                         \
    ss_d += P0.x*P0.x + P0.y*P0.y + P0.z*P0.z + P0.w*P0.w;                    \
    ss_d += P1.x*P1.x + P1.y*P1.y + P1.z*P1.z + P1.w*P1.w;                    \
    ss_d += P2.x*P2.x + P2.y*P2.y + P2.z*P2.z + P2.w*P2.w;                    \
    ss_d += P3.x*P3.x + P3.y*P3.y + P3.z*P3.z + P3.w*P3.w;                    \
    {                                                                         \
        float xa[8] = { P0.x, P0.y, P0.z, P0.w, P1.x, P1.y, P1.z, P1.w };     \
        float xb[8] = { P2.x, P2.y, P2.z, P2.w, P3.x, P3.y, P3.z, P3.w };     \
        half8 hha, hla, hhb, hlb;                                             \
        _Pragma("unroll")                                                     \
        for (int e = 0; e < 8; ++e) {                                         \
            float x = xa[e]; _Float16 hv = (_Float16)x;                       \
            hha[e] = hv; hla[e] = (_Float16)(x - (float)hv);                  \
            float y = xb[e]; _Float16 hw = (_Float16)y;                       \
            hhb[e] = hw; hlb[e] = (_Float16)(y - (float)hw);                  \
        }                                                                     \
        *(half8*)(Bimg + bo_base)              = hha;                         \
        *(half8*)(Bimg + bo_base + 1024)       = hla;                         \
        *(half8*)(Bimg + bo_base + 256)        = hhb;                         \
        *(half8*)(Bimg + bo_base + 256 + 1024) = hlb;                         \
    }                                                                         \
    if (ISLAST) ssPart[t] = ss_d;                                             \
    asm volatile("s_waitcnt lgkmcnt(0)" ::: "memory");                        \
    __builtin_amdgcn_s_barrier();                                             \
    if ((ISLAST) && t < 128) {                                                \
        float sst = ssPart[t] + ssPart[t + 128];                              \
        invS[t] = mymask ? (1.0f / fmaxf(sqrtf(sst), EPSN)) : 0.0f;           \
    }                                                                         \
    {                                                                         \
        int lo = lane << 4;                                                   \
        half8 a0h = *(const half8*)(Aimg + (((C) * 2 + 0) << 10) + lo);       \
        half8 a0l = *(const half8*)(Aimg + (((C) * 2 + 1) << 10) + lo);       \
        half8 a1h = *(const half8*)(Aimg + (((4 + (C)) * 2 + 0) << 10) + lo); \
        half8 a1l = *(const half8*)(Aimg + (((4 + (C)) * 2 + 1) << 10) + lo); \
        _Pragma("unroll")                                                     \
        for (int nt = 0; nt < 2; ++nt) {                                      \
            int tile = w * 2 + nt;                                            \
            half8 bh = *(const half8*)(Bimg + tile * 2048 + lo);              \
            half8 bl = *(const half8*)(Bimg + tile * 2048 + 1024 + lo);       \
            acc[0][nt] = __builtin_amdgcn_mfma_f32_16x16x32_f16(a0l, bh, acc[0][nt], 0, 0, 0); \
            acc[0][nt] = __builtin_amdgcn_mfma_f32_16x16x32_f16(a0h, bl, acc[0][nt], 0, 0, 0); \
            acc[0][nt] = __builtin_amdgcn_mfma_f32_16x16x32_f16(a0h, bh, acc[0][nt], 0, 0, 0); \
            acc[1][nt] = __builtin_amdgcn_mfma_f32_16x16x32_f16(a1l, bh, acc[1][nt], 0, 0, 0); \
            acc[1][nt] = __builtin_amdgcn_mfma_f32_16x16x32_f16(a1h, bl, acc[1][nt], 0, 0, 0); \
            acc[1][nt] = __builtin_amdgcn_mfma_f32_16x16x32_f16(a1h, bh, acc[1][nt], 0, 0, 0); \
        }                                                                     \
    }                                                                         \
    asm volatile("s_waitcnt lgkmcnt(0)" ::: "memory");                        \
    __builtin_amdgcn_s_barrier();                                             \
} while (0)

    CHUNK(0, rA0, rA1, rA2, rA3, rB0, rB1, rB2, rB3, false);
    CHUNK(1, rB0, rB1, rB2, rB3, rA0, rA1, rA2, rA3, false);
    CHUNK(2, rA0, rA1, rA2, rA3, rB0, rB1, rB2, rB3, false);
    CHUNK(3, rB0, rB1, rB2, rB3, rA0, rA1, rA2, rA3, true);
#undef CHUNK

    // ---- epilogue: inv-norm, max over this block's 128 tokens ----
    float inv0 = invS[w * 32 + col];
    float inv1 = invS[w * 32 + 16 + col];
    float m8[8];
#pragma unroll
    for (int qt = 0; qt < 2; ++qt)
#pragma unroll
        for (int rr = 0; rr < 4; ++rr)
            m8[qt * 4 + rr] = fmaxf(acc[qt][0][rr] * inv0, acc[qt][1][rr] * inv1);
#pragma unroll
    for (int off = 1; off < 16; off <<= 1)
#pragma unroll
        for (int i = 0; i < 8; ++i) m8[i] = fmaxf(m8[i], __shfl_xor(m8[i], off));
    if (col == 0) {
        int rg = lane >> 4;   // C/D: row = (lane>>4)*4 + reg (m89-verified)
#pragma unroll
        for (int qt = 0; qt < 2; ++qt)
#pragma unroll
            for (int rr = 0; rr < 4; ++rr) wq[w][qt * 16 + rg * 4 + rr] = m8[qt * 4 + rr];
    }
    __syncthreads();
    if (w == 0 && lane < 32) {
        float v = fmaxf(fmaxf(wq[0][lane], wq[1][lane]), fmaxf(wq[2][lane], wq[3][lane]));
        pmax[(size_t)g * 32 + lane] = v;
    }
}

// ---------------------------------------------------------------------------
// lossb_kernel: one block per b (r3-validated). Each block reads only its
// 4 KB pmax slice (parallel gather across 64 CUs), combines the 2 half-block
// maxes into scores, computes this b's 256 pair losses -> partial[b].
// ---------------------------------------------------------------------------
__global__ __launch_bounds__(256) void lossb_kernel(const float* __restrict__ pmax,
                                                    const float* __restrict__ labels,
                                                    float* __restrict__ partial) {
    __shared__ float pmL[1024];
    __shared__ float sc[16], ysS[16], idxS[16];
    __shared__ float wsum[4];
    int b = blockIdx.x, t = threadIdx.x;
    ((float4*)pmL)[t] = ((const float4*)(pmax + (size_t)b * 1024))[t];
    if (t < 16) { ysS[t] = labels[b * 32 + t]; idxS[t] = labels[b * 32 + 16 + t]; }
    __syncthreads();
    {
        int n = t >> 4, qq = t & 15;
        // layout pmL[n*64 + h*32 + q]; q = qq and qq+16
        float v = fmaxf(pmL[n * 64 + qq],      pmL[n * 64 + 32 + qq])
                + fmaxf(pmL[n * 64 + 16 + qq], pmL[n * 64 + 48 + qq]);
        v += __shfl_xor(v, 1); v += __shfl_xor(v, 2);
        v += __shfl_xor(v, 4); v += __shfl_xor(v, 8);
        if (qq == 0) sc[n] = v;
    }
    __syncthreads();
    int i = t >> 4, j = t & 15;
    float v = 0.f;
    if (ysS[i] - ysS[j] > 0.f) {
        float wgt = fabsf(idxS[i] - idxS[j]);
        float d = (i <= j) ? (sc[i] - sc[j]) : 0.f;
        v = log1pf(expf(-d)) * wgt;
    }
#pragma unroll
    for (int off = 1; off < 64; off <<= 1) v += __shfl_xor(v, off);
    int lane = t & 63;
    if (lane == 0) wsum[t >> 6] = v;
    __syncthreads();
    if (t == 0) partial[b] = wsum[0] + wsum[1] + wsum[2] + wsum[3];
}

__global__ void lossfin_kernel(const float* __restrict__ partial, float* __restrict__ out) {
    int t = threadIdx.x;   // 64 threads, one wave
    float v = partial[t];
#pragma unroll
    for (int off = 1; off < 64; off <<= 1) v += __shfl_xor(v, off);
    if (t == 0) out[0] = v;
}

// ---------------------------------------------------------------------------
extern "C" void kernel_launch(void* const* d_in, const int* in_sizes, int n_in,
                              void* d_out, int out_size, void* d_ws, size_t ws_size,
                              hipStream_t stream) {
    const float* qr     = (const float*)d_in[0];   // (64,32,128) f32
    const float* doc    = (const float*)d_in[1];   // (64,16,256,128) f32
    const int*   dmask  = (const int*)d_in[2];     // (64,16,256) i32
    const float* labels = (const float*)d_in[3];   // (64,32) f32
    float* out = (float*)d_out;

    float* pmax    = (float*)d_ws;                 // 2048*32 f32 = 256 KB
    float* partial = pmax + 2048 * 32;             // 64 f32

    scores_kernel<<<2048, 256, 0, stream>>>(qr, doc, dmask, pmax);
    lossb_kernel<<<64, 256, 0, stream>>>(pmax, labels, partial);
    lossfin_kernel<<<1, 64, 0, stream>>>(partial, out);
}

// Round 9
// 34.626 us; speedup vs baseline: 1.6148x; 1.0134x over previous
//
#include <hip/hip_runtime.h>
#include <cmath>

#define EPSN 1e-12f

typedef _Float16 half8 __attribute__((ext_vector_type(8)));
typedef float f32x4 __attribute__((ext_vector_type(4)));

// ---------------------------------------------------------------------------
// scores_kernel: r4 structure (validated 34.9 us total), prefetch depth 2.
// One block per (b, n, half). 256 threads = 4 waves. Thread (tok=t&127,
// kh=t>>7) owns 64B of its token's row per K-chunk. 4 K-chunks of 32; f16
// hi/lo 3-term MFMA; fp32 sum-of-squares in regs, inv-norm in epilogue.
// THREE rotating register sets (48 VGPR) keep 2 chunks of loads in flight
// (~1300cy lead > ~900cy HBM latency); lgkmcnt-only barriers never drain vm.
// Output: pmax[g*32 + q] = per-q max over this block's 128 tokens.
// ---------------------------------------------------------------------------
__global__ __launch_bounds__(256, 4) void scores_kernel(
    const float* __restrict__ qr, const float* __restrict__ doc,
    const int* __restrict__ mask, float* __restrict__ pmax) {
    __shared__ __align__(16) char Aimg[16384];   // [qt2][kstep4][hl2][1024B]
    __shared__ __align__(16) char Bimg[16384];   // [tile8][hl2][kg4*16+col][16B]
    __shared__ float ssPart[256];
    __shared__ float invS[128];
    __shared__ float wq[4][32];

    int t = threadIdx.x, g = blockIdx.x;
    int bn = g >> 1, h = g & 1, b = g >> 5;
    int w = t >> 6, lane = t & 63, col = lane & 15;
    int tok = t & 127, kh = t >> 7;

    // ---- q loads first (L2-hot, gate only the prologue) ----
    int row = t >> 3, jb = t & 7;
    const float4* qsrc = (const float4*)(qr + ((size_t)b * 32 + row) * 128 + jb * 16);
    float4 v0 = qsrc[0], v1 = qsrc[1], v2 = qsrc[2], v3 = qsrc[3];

    // ---- doc prefetch: chunks 0 and 1 (8 loads in flight) ----
    const float4* dsrc = (const float4*)(doc + ((size_t)bn * 256 + h * 128 + tok) * 128) + kh * 4;
    float4 rA0 = dsrc[0],  rA1 = dsrc[1],  rA2 = dsrc[2],  rA3 = dsrc[3];
    float4 rB0 = dsrc[8],  rB1 = dsrc[9],  rB2 = dsrc[10], rB3 = dsrc[11];
    float4 rC0, rC1, rC2, rC3;
    int mymask = 0;
    if (t < 128) mymask = mask[bn * 256 + h * 128 + t];

    // ---- q prologue: normalize + f16 hi/lo split + A-image (r4-exact) ----
    {
        float ss = v0.x*v0.x + v0.y*v0.y + v0.z*v0.z + v0.w*v0.w
                 + v1.x*v1.x + v1.y*v1.y + v1.z*v1.z + v1.w*v1.w
                 + v2.x*v2.x + v2.y*v2.y + v2.z*v2.z + v2.w*v2.w
                 + v3.x*v3.x + v3.y*v3.y + v3.z*v3.z + v3.w*v3.w;
        ss += __shfl_xor(ss, 1); ss += __shfl_xor(ss, 2); ss += __shfl_xor(ss, 4);
        float inv = 1.0f / fmaxf(sqrtf(ss), EPSN);
        int qt = row >> 4, kstep = jb >> 1;
        float4 vv[4] = { v0, v1, v2, v3 };
#pragma unroll
        for (int khh = 0; khh < 2; ++khh) {
            float xs[8] = { vv[2*khh].x,   vv[2*khh].y,   vv[2*khh].z,   vv[2*khh].w,
                            vv[2*khh+1].x, vv[2*khh+1].y, vv[2*khh+1].z, vv[2*khh+1].w };
            half8 hh, hl;
#pragma unroll
            for (int e = 0; e < 8; ++e) {
                float x = xs[e] * inv;
                _Float16 hv = (_Float16)x;
                hh[e] = hv;
                hl[e] = (_Float16)(x - (float)hv);
            }
            int quad = (jb & 1) * 2 + khh;
            int base = ((qt * 4 + kstep) * 2) * 1024 + ((row & 15) + quad * 16) * 16;
            *(half8*)(Aimg + base)        = hh;
            *(half8*)(Aimg + base + 1024) = hl;
        }
    }
    asm volatile("s_waitcnt lgkmcnt(0)" ::: "memory");
    __builtin_amdgcn_s_barrier();

    f32x4 acc[2][2];
    f32x4 zero = {0.f, 0.f, 0.f, 0.f};
    acc[0][0] = zero; acc[0][1] = zero; acc[1][0] = zero; acc[1][1] = zero;
    float ss_d = 0.f;

    int tile8 = tok >> 4;
    int bo_base = tile8 * 2048 + (2 * kh) * 256 + (tok & 15) * 16;

#define CHUNK(C, P0, P1, P2, P3, N0, N1, N2, N3, PREF, ISLAST) do {           \
    if (PREF) {                                                               \
        N0 = dsrc[(C + 2) * 8 + 0]; N1 = dsrc[(C + 2) * 8 + 1];               \
        N2 = dsrc[(C + 2) * 8 + 2]; N3 = dsrc[(C + 2) * 8 + 3];               \
    }                                                                         \
    ss_d += P0.x*P0.x + P0.y*P0.y + P0.z*P0.z + P0.w*P0.w;                    \
    ss_d += P1.x*P1.x + P1.y*P1.y + P1.z*P1.z + P1.w*P1.w;                    \
    ss_d += P2.x*P2.x + P2.y*P2.y + P2.z*P2.z + P2.w*P2.w;                    \
    ss_d += P3.x*P3.x + P3.y*P3.y + P3.z*P3.z + P3.w*P3.w;                    \
    {                                                                         \
        float xa[8] = { P0.x, P0.y, P0.z, P0.w, P1.x, P1.y, P1.z, P1.w };     \
        float xb[8] = { P2.x, P2.y, P2.z, P2.w, P3.x, P3.y, P3.z, P3.w };     \
        half8 hha, hla, hhb, hlb;                                             \
        _Pragma("unroll")                                                     \
        for (int e = 0; e < 8; ++e) {                                         \
            float x = xa[e]; _Float16 hv = (_Float16)x;                       \
            hha[e] = hv; hla[e] = (_Float16)(x - (float)hv);                  \
            float y = xb[e]; _Float16 hw = (_Float16)y;                       \
            hhb[e] = hw; hlb[e] = (_Float16)(y - (float)hw);                  \
        }                                                                     \
        *(half8*)(Bimg + bo_base)              = hha;                         \
        *(half8*)(Bimg + bo_base + 1024)       = hla;                         \
        *(half8*)(Bimg + bo_base + 256)        = hhb;                         \
        *(half8*)(Bimg + bo_base + 256 + 1024) = hlb;                         \
    }                                                                         \
    if (ISLAST) ssPart[t] = ss_d;                                             \
    asm volatile("s_waitcnt lgkmcnt(0)" ::: "memory");                        \
    __builtin_amdgcn_s_barrier();                                             \
    if ((ISLAST) && t < 128) {                                                \
        float sst = ssPart[t] + ssPart[t + 128];                              \
        invS[t] = mymask ? (1.0f / fmaxf(sqrtf(sst), EPSN)) : 0.0f;           \
    }                                                                         \
    {                                                                         \
        int lo = lane << 4;                                                   \
        half8 a0h = *(const half8*)(Aimg + (((C) * 2 + 0) << 10) + lo);       \
        half8 a0l = *(const half8*)(Aimg + (((C) * 2 + 1) << 10) + lo);       \
        half8 a1h = *(const half8*)(Aimg + (((4 + (C)) * 2 + 0) << 10) + lo); \
        half8 a1l = *(const half8*)(Aimg + (((4 + (C)) * 2 + 1) << 10) + lo); \
        _Pragma("unroll")                                                     \
        for (int nt = 0; nt < 2; ++nt) {                                      \
            int tile = w * 2 + nt;                                            \
            half8 bh = *(const half8*)(Bimg + tile * 2048 + lo);              \
            half8 bl = *(const half8*)(Bimg + tile * 2048 + 1024 + lo);       \
            acc[0][nt] = __builtin_amdgcn_mfma_f32_16x16x32_f16(a0l, bh, acc[0][nt], 0, 0, 0); \
            acc[0][nt] = __builtin_amdgcn_mfma_f32_16x16x32_f16(a0h, bl, acc[0][nt], 0, 0, 0); \
            acc[0][nt] = __builtin_amdgcn_mfma_f32_16x16x32_f16(a0h, bh, acc[0][nt], 0, 0, 0); \
            acc[1][nt] = __builtin_amdgcn_mfma_f32_16x16x32_f16(a1l, bh, acc[1][nt], 0, 0, 0); \
            acc[1][nt] = __builtin_amdgcn_mfma_f32_16x16x32_f16(a1h, bl, acc[1][nt], 0, 0, 0); \
            acc[1][nt] = __builtin_amdgcn_mfma_f32_16x16x32_f16(a1h, bh, acc[1][nt], 0, 0, 0); \
        }                                                                     \
    }                                                                         \
    asm volatile("s_waitcnt lgkmcnt(0)" ::: "memory");                        \
    __builtin_amdgcn_s_barrier();                                             \
} while (0)

    // rotation: c0=A c1=B c2=C c3=A; prefetch c+2 during chunk c
    CHUNK(0, rA0, rA1, rA2, rA3, rC0, rC1, rC2, rC3, 1, false);
    CHUNK(1, rB0, rB1, rB2, rB3, rA0, rA1, rA2, rA3, 1, false);
    CHUNK(2, rC0, rC1, rC2, rC3, rB0, rB1, rB2, rB3, 0, false);
    CHUNK(3, rA0, rA1, rA2, rA3, rB0, rB1, rB2, rB3, 0, true);
#undef CHUNK

    // ---- epilogue: inv-norm, max over this block's 128 tokens ----
    float inv0 = invS[w * 32 + col];
    float inv1 = invS[w * 32 + 16 + col];
    float m8[8];
#pragma unroll
    for (int qt = 0; qt < 2; ++qt)
#pragma unroll
        for (int rr = 0; rr < 4; ++rr)
            m8[qt * 4 + rr] = fmaxf(acc[qt][0][rr] * inv0, acc[qt][1][rr] * inv1);
#pragma unroll
    for (int off = 1; off < 16; off <<= 1)
#pragma unroll
        for (int i = 0; i < 8; ++i) m8[i] = fmaxf(m8[i], __shfl_xor(m8[i], off));
    if (col == 0) {
        int rg = lane >> 4;   // C/D: row = (lane>>4)*4 + reg (m89-verified)
#pragma unroll
        for (int qt = 0; qt < 2; ++qt)
#pragma unroll
            for (int rr = 0; rr < 4; ++rr) wq[w][qt * 16 + rg * 4 + rr] = m8[qt * 4 + rr];
    }
    __syncthreads();
    if (w == 0 && lane < 32) {
        float v = fmaxf(fmaxf(wq[0][lane], wq[1][lane]), fmaxf(wq[2][lane], wq[3][lane]));
        pmax[(size_t)g * 32 + lane] = v;
    }
}

// ---------------------------------------------------------------------------
// lossb_kernel: one block per b (r3-validated). Parallel 4 KB pmax gather,
// combine half-block maxes into scores, 256 pair losses -> partial[b].
// ---------------------------------------------------------------------------
__global__ __launch_bounds__(256) void lossb_kernel(const float* __restrict__ pmax,
                                                    const float* __restrict__ labels,
                                                    float* __restrict__ partial) {
    __shared__ float pmL[1024];
    __shared__ float sc[16], ysS[16], idxS[16];
    __shared__ float wsum[4];
    int b = blockIdx.x, t = threadIdx.x;
    ((float4*)pmL)[t] = ((const float4*)(pmax + (size_t)b * 1024))[t];
    if (t < 16) { ysS[t] = labels[b * 32 + t]; idxS[t] = labels[b * 32 + 16 + t]; }
    __syncthreads();
    {
        int n = t >> 4, qq = t & 15;
        float v = fmaxf(pmL[n * 64 + qq],      pmL[n * 64 + 32 + qq])
                + fmaxf(pmL[n * 64 + 16 + qq], pmL[n * 64 + 48 + qq]);
        v += __shfl_xor(v, 1); v += __shfl_xor(v, 2);
        v += __shfl_xor(v, 4); v += __shfl_xor(v, 8);
        if (qq == 0) sc[n] = v;
    }
    __syncthreads();
    int i = t >> 4, j = t & 15;
    float v = 0.f;
    if (ysS[i] - ysS[j] > 0.f) {
        float wgt = fabsf(idxS[i] - idxS[j]);
        float d = (i <= j) ? (sc[i] - sc[j]) : 0.f;
        v = log1pf(expf(-d)) * wgt;
    }
#pragma unroll
    for (int off = 1; off < 64; off <<= 1) v += __shfl_xor(v, off);
    int lane = t & 63;
    if (lane == 0) wsum[t >> 6] = v;
    __syncthreads();
    if (t == 0) partial[b] = wsum[0] + wsum[1] + wsum[2] + wsum[3];
}

__global__ void lossfin_kernel(const float* __restrict__ partial, float* __restrict__ out) {
    int t = threadIdx.x;   // 64 threads, one wave
    float v = partial[t];
#pragma unroll
    for (int off = 1; off < 64; off <<= 1) v += __shfl_xor(v, off);
    if (t == 0) out[0] = v;
}

// ---------------------------------------------------------------------------
extern "C" void kernel_launch(void* const* d_in, const int* in_sizes, int n_in,
                              void* d_out, int out_size, void* d_ws, size_t ws_size,
                              hipStream_t stream) {
    const float* qr     = (const float*)d_in[0];   // (64,32,128) f32
    const float* doc    = (const float*)d_in[1];   // (64,16,256,128) f32
    const int*   dmask  = (const int*)d_in[2];     // (64,16,256) i32
    const float* labels = (const float*)d_in[3];   // (64,32) f32
    float* out = (float*)d_out;

    float* pmax    = (float*)d_ws;                 // 2048*32 f32 = 256 KB
    float* partial = pmax + 2048 * 32;             // 64 f32

    scores_kernel<<<2048, 256, 0, stream>>>(qr, doc, dmask, pmax);
    lossb_kernel<<<64, 256, 0, stream>>>(pmax, labels, partial);
    lossfin_kernel<<<1, 64, 0, stream>>>(partial, out);
}

// Round 10
// 30.052 us; speedup vs baseline: 1.8606x; 1.1522x over previous
//
#include <hip/hip_runtime.h>
#include <cmath>

#define EPSN 1e-12f

typedef _Float16 half8 __attribute__((ext_vector_type(8)));
typedef float f32x4 __attribute__((ext_vector_type(4)));

// ---------------------------------------------------------------------------
// scores_kernel: r4 hot-path structure + mask compaction (skip loading the
// ~50% masked tokens entirely; their sim is exactly 0 in the reference).
// One block per (b, n, half), 256 threads = 4 waves. Front-packed compact
// slot list; pad slots: no loads, zeroed B-image (chunk 0), invS=0 -> they
// inject 0 into the per-q max exactly when masked tokens exist (= reference
// semantics). f16 hi/lo 3-term MFMA; depth-2 register prefetch rotation;
// lgkmcnt-only barriers keep doc loads in flight across barriers.
// ---------------------------------------------------------------------------
__global__ __launch_bounds__(256, 4) void scores_kernel(
    const float* __restrict__ qr, const float* __restrict__ doc,
    const int* __restrict__ mask, float* __restrict__ pmax) {
    __shared__ __align__(16) char Aimg[16384];   // [qt2][kstep4][hl2][1024B]
    __shared__ __align__(16) char Bimg[16384];   // [tile8][hl2][kg4*16+col][16B]
    __shared__ float ssPart[256];
    __shared__ float invS[128];
    __shared__ int   compactS[128];
    __shared__ int   cntW[2];
    __shared__ float wq[4][32];

    int t = threadIdx.x, g = blockIdx.x;
    int bn = g >> 1, h = g & 1, b = g >> 5;
    int w = t >> 6, lane = t & 63, col = lane & 15;

    // ---- q loads first (arrive during compaction) ----
    int row = t >> 3, jb = t & 7;
    const float4* qsrc = (const float4*)(qr + ((size_t)b * 32 + row) * 128 + jb * 16);
    float4 v0 = qsrc[0], v1 = qsrc[1], v2 = qsrc[2], v3 = qsrc[3];

    // ---- mask load + ballot compaction (front-packed slot -> token) ----
    int myMask = 0;
    if (t < 128) myMask = mask[bn * 256 + h * 128 + t];
    unsigned long long bal = __ballot(myMask != 0);
    if (t < 128 && lane == 0) cntW[w] = __popcll(bal);
    __syncthreads();
    int cnt = cntW[0] + cntW[1];
    if (myMask) {
        int prefix = __popcll(bal & ((1ull << lane) - 1));
        int basec = (w == 1) ? cntW[0] : 0;
        compactS[basec + prefix] = t;
    }
    __syncthreads();

    int s = t & 127, kh = t >> 7;
    bool real = (s < cnt);
    int tokc = real ? compactS[s] : 0;

    // ---- doc prefetch: chunks 0 and 1 (guarded; exec-masked => no traffic
    //      for pad lanes; front-packing empties waves 1,3) ----
    const float4* dsrc = (const float4*)(doc + ((size_t)bn * 256 + h * 128 + tokc) * 128) + kh * 4;
    float4 rA0, rA1, rA2, rA3, rB0, rB1, rB2, rB3, rC0, rC1, rC2, rC3;
    if (real) {
        rA0 = dsrc[0];  rA1 = dsrc[1];  rA2 = dsrc[2],  rA3 = dsrc[3];
        rB0 = dsrc[8];  rB1 = dsrc[9];  rB2 = dsrc[10]; rB3 = dsrc[11];
    }

    // ---- q prologue: normalize + f16 hi/lo split + A-image (r4-exact) ----
    {
        float ss = v0.x*v0.x + v0.y*v0.y + v0.z*v0.z + v0.w*v0.w
                 + v1.x*v1.x + v1.y*v1.y + v1.z*v1.z + v1.w*v1.w
                 + v2.x*v2.x + v2.y*v2.y + v2.z*v2.z + v2.w*v2.w
                 + v3.x*v3.x + v3.y*v3.y + v3.z*v3.z + v3.w*v3.w;
        ss += __shfl_xor(ss, 1); ss += __shfl_xor(ss, 2); ss += __shfl_xor(ss, 4);
        float inv = 1.0f / fmaxf(sqrtf(ss), EPSN);
        int qt = row >> 4, kstep = jb >> 1;
        float4 vv[4] = { v0, v1, v2, v3 };
#pragma unroll
        for (int khh = 0; khh < 2; ++khh) {
            float xs[8] = { vv[2*khh].x,   vv[2*khh].y,   vv[2*khh].z,   vv[2*khh].w,
                            vv[2*khh+1].x, vv[2*khh+1].y, vv[2*khh+1].z, vv[2*khh+1].w };
            half8 hh, hl;
#pragma unroll
            for (int e = 0; e < 8; ++e) {
                float x = xs[e] * inv;
                _Float16 hv = (_Float16)x;
                hh[e] = hv;
                hl[e] = (_Float16)(x - (float)hv);
            }
            int quad = (jb & 1) * 2 + khh;
            int base = ((qt * 4 + kstep) * 2) * 1024 + ((row & 15) + quad * 16) * 16;
            *(half8*)(Aimg + base)        = hh;
            *(half8*)(Aimg + base + 1024) = hl;
        }
    }
    asm volatile("s_waitcnt lgkmcnt(0)" ::: "memory");
    __builtin_amdgcn_s_barrier();

    f32x4 acc[2][2];
    f32x4 zero = {0.f, 0.f, 0.f, 0.f};
    acc[0][0] = zero; acc[0][1] = zero; acc[1][0] = zero; acc[1][1] = zero;
    float ss_d = 0.f;

    int tile8 = s >> 4;
    int bo_base = tile8 * 2048 + (2 * kh) * 256 + (s & 15) * 16;

#define CHUNK(C, P0, P1, P2, P3, N0, N1, N2, N3, PREF, ISLAST) do {           \
    if ((PREF) && real) {                                                     \
        N0 = dsrc[(C + 2) * 8 + 0]; N1 = dsrc[(C + 2) * 8 + 1];               \
        N2 = dsrc[(C + 2) * 8 + 2]; N3 = dsrc[(C + 2) * 8 + 3];               \
    }                                                                         \
    if (real) {                                                               \
        ss_d += P0.x*P0.x + P0.y*P0.y + P0.z*P0.z + P0.w*P0.w;                \
        ss_d += P1.x*P1.x + P1.y*P1.y + P1.z*P1.z + P1.w*P1.w;                \
        ss_d += P2.x*P2.x + P2.y*P2.y + P2.z*P2.z + P2.w*P2.w;                \
        ss_d += P3.x*P3.x + P3.y*P3.y + P3.z*P3.z + P3.w*P3.w;                \
        float xa[8] = { P0.x, P0.y, P0.z, P0.w, P1.x, P1.y, P1.z, P1.w };     \
        float xb[8] = { P2.x, P2.y, P2.z, P2.w, P3.x, P3.y, P3.z, P3.w };     \
        half8 hha, hla, hhb, hlb;                                             \
        _Pragma("unroll")                                                     \
        for (int e = 0; e < 8; ++e) {                                         \
            float x = xa[e]; _Float16 hv = (_Float16)x;                       \
            hha[e] = hv; hla[e] = (_Float16)(x - (float)hv);                  \
            float y = xb[e]; _Float16 hw = (_Float16)y;                       \
            hhb[e] = hw; hlb[e] = (_Float16)(y - (float)hw);                  \
        }                                                                     \
        *(half8*)(Bimg + bo_base)              = hha;                         \
        *(half8*)(Bimg + bo_base + 1024)       = hla;                         \
        *(half8*)(Bimg + bo_base + 256)        = hhb;                         \
        *(half8*)(Bimg + bo_base + 256 + 1024) = hlb;                         \
    } else if ((C) == 0) {                                                    \
        half8 hz = {0,0,0,0,0,0,0,0};                                         \
        *(half8*)(Bimg + bo_base)              = hz;                          \
        *(half8*)(Bimg + bo_base + 1024)       = hz;                          \
        *(half8*)(Bimg + bo_base + 256)        = hz;                          \
        *(half8*)(Bimg + bo_base + 256 + 1024) = hz;                          \
    }                                                                         \
    if (ISLAST) ssPart[t] = ss_d;                                             \
    asm volatile("s_waitcnt lgkmcnt(0)" ::: "memory");                        \
    __builtin_amdgcn_s_barrier();                                             \
    if ((ISLAST) && t < 128) {                                                \
        float sst = ssPart[t] + ssPart[t + 128];                              \
        invS[t] = (t < cnt) ? (1.0f / fmaxf(sqrtf(sst), EPSN)) : 0.0f;        \
    }                                                                         \
    {                                                                         \
        int lo = lane << 4;                                                   \
        half8 a0h = *(const half8*)(Aimg + (((C) * 2 + 0) << 10) + lo);       \
        half8 a0l = *(const half8*)(Aimg + (((C) * 2 + 1) << 10) + lo);       \
        half8 a1h = *(const half8*)(Aimg + (((4 + (C)) * 2 + 0) << 10) + lo); \
        half8 a1l = *(const half8*)(Aimg + (((4 + (C)) * 2 + 1) << 10) + lo); \
        _Pragma("unroll")                                                     \
        for (int nt = 0; nt < 2; ++nt) {                                      \
            int tile = w * 2 + nt;                                            \
            half8 bh = *(const half8*)(Bimg + tile * 2048 + lo);              \
            half8 bl = *(const half8*)(Bimg + tile * 2048 + 1024 + lo);       \
            acc[0][nt] = __builtin_amdgcn_mfma_f32_16x16x32_f16(a0l, bh, acc[0][nt], 0, 0, 0); \
            acc[0][nt] = __builtin_amdgcn_mfma_f32_16x16x32_f16(a0h, bl, acc[0][nt], 0, 0, 0); \
            acc[0][nt] = __builtin_amdgcn_mfma_f32_16x16x32_f16(a0h, bh, acc[0][nt], 0, 0, 0); \
            acc[1][nt] = __builtin_amdgcn_mfma_f32_16x16x32_f16(a1l, bh, acc[1][nt], 0, 0, 0); \
            acc[1][nt] = __builtin_amdgcn_mfma_f32_16x16x32_f16(a1h, bl, acc[1][nt], 0, 0, 0); \
            acc[1][nt] = __builtin_amdgcn_mfma_f32_16x16x32_f16(a1h, bh, acc[1][nt], 0, 0, 0); \
        }                                                                     \
    }                                                                         \
    asm volatile("s_waitcnt lgkmcnt(0)" ::: "memory");                        \
    __builtin_amdgcn_s_barrier();                                             \
} while (0)

    // rotation: c0=A c1=B c2=C c3=A; prefetch c+2 during chunk c
    CHUNK(0, rA0, rA1, rA2, rA3, rC0, rC1, rC2, rC3, 1, false);
    CHUNK(1, rB0, rB1, rB2, rB3, rA0, rA1, rA2, rA3, 1, false);
    CHUNK(2, rC0, rC1, rC2, rC3, rB0, rB1, rB2, rB3, 0, false);
    CHUNK(3, rA0, rA1, rA2, rA3, rB0, rB1, rB2, rB3, 0, true);
#undef CHUNK

    // ---- epilogue: inv-norm, max over this block's slots (r4-exact) ----
    float inv0 = invS[w * 32 + col];
    float inv1 = invS[w * 32 + 16 + col];
    float m8[8];
#pragma unroll
    for (int qt = 0; qt < 2; ++qt)
#pragma unroll
        for (int rr = 0; rr < 4; ++rr)
            m8[qt * 4 + rr] = fmaxf(acc[qt][0][rr] * inv0, acc[qt][1][rr] * inv1);
#pragma unroll
    for (int off = 1; off < 16; off <<= 1)
#pragma unroll
        for (int i = 0; i < 8; ++i) m8[i] = fmaxf(m8[i], __shfl_xor(m8[i], off));
    if (col == 0) {
        int rg = lane >> 4;   // C/D: row = (lane>>4)*4 + reg (m89-verified)
#pragma unroll
        for (int qt = 0; qt < 2; ++qt)
#pragma unroll
            for (int rr = 0; rr < 4; ++rr) wq[w][qt * 16 + rg * 4 + rr] = m8[qt * 4 + rr];
    }
    __syncthreads();
    if (w == 0 && lane < 32) {
        float v = fmaxf(fmaxf(wq[0][lane], wq[1][lane]), fmaxf(wq[2][lane], wq[3][lane]));
        pmax[(size_t)g * 32 + lane] = v;
    }
}

// ---------------------------------------------------------------------------
// lossb_kernel: one block per b (r3/r8-validated). Parallel 4 KB pmax gather,
// combine half-block maxes into scores, 256 pair losses -> partial[b].
// ---------------------------------------------------------------------------
__global__ __launch_bounds__(256) void lossb_kernel(const float* __restrict__ pmax,
                                                    const float* __restrict__ labels,
                                                    float* __restrict__ partial) {
    __shared__ float pmL[1024];
    __shared__ float sc[16], ysS[16], idxS[16];
    __shared__ float wsum[4];
    int b = blockIdx.x, t = threadIdx.x;
    ((float4*)pmL)[t] = ((const float4*)(pmax + (size_t)b * 1024))[t];
    if (t < 16) { ysS[t] = labels[b * 32 + t]; idxS[t] = labels[b * 32 + 16 + t]; }
    __syncthreads();
    {
        int n = t >> 4, qq = t & 15;
        float v = fmaxf(pmL[n * 64 + qq],      pmL[n * 64 + 32 + qq])
                + fmaxf(pmL[n * 64 + 16 + qq], pmL[n * 64 + 48 + qq]);
        v += __shfl_xor(v, 1); v += __shfl_xor(v, 2);
        v += __shfl_xor(v, 4); v += __shfl_xor(v, 8);
        if (qq == 0) sc[n] = v;
    }
    __syncthreads();
    int i = t >> 4, j = t & 15;
    float v = 0.f;
    if (ysS[i] - ysS[j] > 0.f) {
        float wgt = fabsf(idxS[i] - idxS[j]);
        float d = (i <= j) ? (sc[i] - sc[j]) : 0.f;
        v = log1pf(expf(-d)) * wgt;
    }
#pragma unroll
    for (int off = 1; off < 64; off <<= 1) v += __shfl_xor(v, off);
    int lane = t & 63;
    if (lane == 0) wsum[t >> 6] = v;
    __syncthreads();
    if (t == 0) partial[b] = wsum[0] + wsum[1] + wsum[2] + wsum[3];
}

__global__ void lossfin_kernel(const float* __restrict__ partial, float* __restrict__ out) {
    int t = threadIdx.x;   // 64 threads, one wave
    float v = partial[t];
#pragma unroll
    for (int off = 1; off < 64; off <<= 1) v += __shfl_xor(v, off);
    if (t == 0) out[0] = v;
}

// ---------------------------------------------------------------------------
extern "C" void kernel_launch(void* const* d_in, const int* in_sizes, int n_in,
                              void* d_out, int out_size, void* d_ws, size_t ws_size,
                              hipStream_t stream) {
    const float* qr     = (const float*)d_in[0];   // (64,32,128) f32
    const float* doc    = (const float*)d_in[1];   // (64,16,256,128) f32
    const int*   dmask  = (const int*)d_in[2];     // (64,16,256) i32
    const float* labels = (const float*)d_in[3];   // (64,32) f32
    float* out = (float*)d_out;

    float* pmax    = (float*)d_ws;                 // 2048*32 f32 = 256 KB
    float* partial = pmax + 2048 * 32;             // 64 f32

    scores_kernel<<<2048, 256, 0, stream>>>(qr, doc, dmask, pmax);
    lossb_kernel<<<64, 256, 0, stream>>>(pmax, labels, partial);
    lossfin_kernel<<<1, 64, 0, stream>>>(partial, out);
}